// Round 3
// baseline (779.076 us; speedup 1.0000x reference)
//
#include <hip/hip_runtime.h>
#include <hip/hip_bf16.h>

typedef unsigned short ushort_t;
typedef __attribute__((ext_vector_type(4))) float v4f;
typedef __attribute__((ext_vector_type(8))) short v8s;

#define FDIM 128
#define KCLUST 16
#define CSTRIDE 264   // combined-row stride in bf16 elems

__device__ __forceinline__ ushort_t f2bf(float x) {
    unsigned int u = __float_as_uint(x);
    unsigned int r = (u + 0x7fffu + ((u >> 16) & 1u)) >> 16;
    return (ushort_t)r;
}

__device__ __forceinline__ float wave_reduce_sum(float v) {
    #pragma unroll
    for (int off = 32; off > 0; off >>= 1) v += __shfl_xor(v, off, 64);
    return v;
}

// ---------------------------------------------------------------------------
// Kernel 1: cast weight (E x 256 f32) -> bf16, padded to Np rows (zeros).
// ---------------------------------------------------------------------------
__global__ void pack_weight(const float* __restrict__ W, ushort_t* __restrict__ Wb,
                            long total, long valid) {
    long i = ((long)blockIdx.x * blockDim.x + threadIdx.x) * 4;
    if (i >= total) return;
    float4 v;
    if (i < valid) v = *(const float4*)(W + i);
    else           v = make_float4(0.f, 0.f, 0.f, 0.f);
    ushort_t* dst = Wb + i;
    dst[0] = f2bf(v.x); dst[1] = f2bf(v.y); dst[2] = f2bf(v.z); dst[3] = f2bf(v.w);
}

// ---------------------------------------------------------------------------
// Kernel 2 (fused): 512 threads = 8 waves, one row b per wave.
// Phase A: build combined[8][256] bf16 in LDS; per (b,s):
//   - neighbor staged in per-wave swizzled LDS; lane (k=l16, blk=quad)
//     computes d_k over 32 feats with center in regs, attention-logit
//     partial folded into the same read pass; ONE xor16/xor32 reduce pair
//     for both d and ln (no butterfly).
//   - att*q broadcast via 16-float LDS; m-dot with mask in regs.
// Phase B: out[8][E] = relu(combined @ Wb^T), m=16 MFMA tile with rows
//   8..15 zeroed; 8 waves stride the E/16 column tiles.
// ---------------------------------------------------------------------------
__global__ __launch_bounds__(512, 6) void fused_agg(
    const int* __restrict__ nodes, const int* __restrict__ neigh_idx,
    const float* __restrict__ self_table, const float* __restrict__ neigh_table,
    const float* __restrict__ center, const float* __restrict__ cluster_mask,
    const float* __restrict__ alpha, const ushort_t* __restrict__ Wb,
    float* __restrict__ out, int B, int S, int E) {

    __shared__ __align__(16) ushort_t comb[16 * CSTRIDE];
    __shared__ __align__(16) float nbuf[8 * 144];   // per-wave swizzled neigh vec
    __shared__ __align__(16) float qbuf[8 * 16];    // per-wave att*q[16]

    int t = threadIdx.x;
    int lane = t & 63, wave = t >> 6;
    int l16 = lane & 15, quad = lane >> 4;   // cluster k = l16, feat-block = quad

    // zero comb rows 8..15 (they feed the m=16 MFMA tile as padding)
    for (int i = t; i < (8 * CSTRIDE) / 2; i += 512)
        ((unsigned*)(comb + 8 * CSTRIDE))[i] = 0u;

    // per-lane constants
    float as0 = alpha[lane], as1 = alpha[lane + 64];

    // center in cluster layout: cc[j] = center[l16][quad*32 + j]
    float cc[32];
    {
        const float* cb = center + l16 * FDIM + quad * 32;
        #pragma unroll
        for (int j = 0; j < 32; j += 4) {
            float4 v = *(const float4*)(cb + j);
            cc[j] = v.x; cc[j+1] = v.y; cc[j+2] = v.z; cc[j+3] = v.w;
        }
    }
    // a_neigh in cluster layout: anc[j] = alpha[128 + quad*32 + j]
    float anc[32];
    {
        const float* ab = alpha + 128 + quad * 32;
        #pragma unroll
        for (int j = 0; j < 32; j += 4) {
            float4 v = *(const float4*)(ab + j);
            anc[j] = v.x; anc[j+1] = v.y; anc[j+2] = v.z; anc[j+3] = v.w;
        }
    }
    // mask in feature layout
    float mk0[KCLUST], mk1[KCLUST];
    #pragma unroll
    for (int kk = 0; kk < KCLUST; kk++) {
        mk0[kk] = cluster_mask[kk * FDIM + lane];
        mk1[kk] = cluster_mask[kk * FDIM + 64 + lane];
    }

    int b0 = blockIdx.x * 8;
    int b = b0 + wave;
    float* nb = nbuf + wave * 144;
    float* qb = qbuf + wave * 16;
    ushort_t* crow = comb + wave * CSTRIDE;

    if (b < B) {
        size_t node = (size_t)nodes[b];
        float s0 = self_table[node * FDIM + lane];
        float s1 = self_table[node * FDIM + 64 + lane];
        float ls = wave_reduce_sum(s0 * as0 + s1 * as1);

        float acc0 = 0.f, acc1 = 0.f, attsum = 0.f;
        const int* nidx = neigh_idx + (size_t)b * S;
        size_t g = (size_t)nidx[0];
        float n0 = neigh_table[g * FDIM + lane];
        float n1 = neigh_table[g * FDIM + 64 + lane];
        for (int s = 0; s < S; s++) {
            float cn0 = n0, cn1 = n1;
            if (s + 1 < S) {
                g = (size_t)nidx[s + 1];
                n0 = neigh_table[g * FDIM + lane];
                n1 = neigh_table[g * FDIM + 64 + lane];
            }
            // stage neigh vec (swizzled: float f at idx f + (f>>5)*4)
            nb[lane + (lane >> 5) * 4] = cn0;
            int f2 = lane + 64;
            nb[f2 + (f2 >> 5) * 4] = cn1;
            // cluster layout: d_k over 32 feats + logit partial, same pass
            float d = 0.f, lnp = 0.f;
            const float* nbb = nb + quad * 36;
            #pragma unroll
            for (int i = 0; i < 8; i++) {
                float4 f4 = *(const float4*)(nbb + i * 4);
                float t0 = f4.x - cc[i*4+0]; d = fmaf(t0, t0, d); lnp = fmaf(f4.x, anc[i*4+0], lnp);
                float t1 = f4.y - cc[i*4+1]; d = fmaf(t1, t1, d); lnp = fmaf(f4.y, anc[i*4+1], lnp);
                float t2 = f4.z - cc[i*4+2]; d = fmaf(t2, t2, d); lnp = fmaf(f4.z, anc[i*4+2], lnp);
                float t3 = f4.w - cc[i*4+3]; d = fmaf(t3, t3, d); lnp = fmaf(f4.w, anc[i*4+3], lnp);
            }
            d   += __shfl_xor(d, 16, 64);   d   += __shfl_xor(d, 32, 64);
            lnp += __shfl_xor(lnp, 16, 64); lnp += __shfl_xor(lnp, 32, 64);
            float att = __expf(fmaxf(ls + lnp, 0.f));
            float q = __fdividef(att, d + 1.0f);   // att*q folded
            if (lane < 16) qb[lane] = q;
            float4 q0 = *(const float4*)(qb + 0);
            float4 q1 = *(const float4*)(qb + 4);
            float4 q2 = *(const float4*)(qb + 8);
            float4 q3 = *(const float4*)(qb + 12);
            float m0, m1;
            m0  = q0.x*mk0[0]  + q0.y*mk0[1]  + q0.z*mk0[2]  + q0.w*mk0[3];
            m0 += q1.x*mk0[4]  + q1.y*mk0[5]  + q1.z*mk0[6]  + q1.w*mk0[7];
            m0 += q2.x*mk0[8]  + q2.y*mk0[9]  + q2.z*mk0[10] + q2.w*mk0[11];
            m0 += q3.x*mk0[12] + q3.y*mk0[13] + q3.z*mk0[14] + q3.w*mk0[15];
            m1  = q0.x*mk1[0]  + q0.y*mk1[1]  + q0.z*mk1[2]  + q0.w*mk1[3];
            m1 += q1.x*mk1[4]  + q1.y*mk1[5]  + q1.z*mk1[6]  + q1.w*mk1[7];
            m1 += q2.x*mk1[8]  + q2.y*mk1[9]  + q2.z*mk1[10] + q2.w*mk1[11];
            m1 += q3.x*mk1[12] + q3.y*mk1[13] + q3.z*mk1[14] + q3.w*mk1[15];
            acc0 += cn0 * m0;
            acc1 += cn1 * m1;
            attsum += att;
        }
        float inv = __fdividef(1.0f, attsum);
        crow[lane]       = f2bf(s0);
        crow[lane + 64]  = f2bf(s1);
        crow[lane + 128] = f2bf(acc0 * inv);
        crow[lane + 192] = f2bf(acc1 * inv);
    } else {
        crow[lane] = 0; crow[lane + 64] = 0;
        crow[lane + 128] = 0; crow[lane + 192] = 0;
    }
    __syncthreads();

    // ---------------- phase B ----------------
    v8s afr[8];
    #pragma unroll
    for (int kk = 0; kk < 8; kk++)
        afr[kk] = *(const v8s*)(comb + l16 * CSTRIDE + kk * 32 + quad * 8);

    int Ntiles = (E + 15) >> 4;
    for (int nt = wave; nt < Ntiles; nt += 8) {
        const ushort_t* wrow = Wb + ((size_t)(nt * 16 + l16)) * 256 + quad * 8;
        v4f acc = {0.f, 0.f, 0.f, 0.f};
        #pragma unroll
        for (int kk = 0; kk < 8; kk++) {
            v8s bfr = *(const v8s*)(wrow + kk * 32);
            acc = __builtin_amdgcn_mfma_f32_16x16x32_bf16(afr[kk], bfr, acc, 0, 0, 0);
        }
        int gcol = nt * 16 + l16;
        if (gcol < E) {
            #pragma unroll
            for (int rr = 0; rr < 4; rr++) {
                int r16 = quad * 4 + rr;
                if (r16 < 8) {
                    int grow = b0 + r16;
                    if (grow < B)
                        out[(size_t)grow * E + gcol] = fmaxf(acc[rr], 0.f);
                }
            }
        }
    }
}

extern "C" void kernel_launch(void* const* d_in, const int* in_sizes, int n_in,
                              void* d_out, int out_size, void* d_ws, size_t ws_size,
                              hipStream_t stream) {
    const int*   nodes        = (const int*)d_in[0];
    const int*   neigh_idx    = (const int*)d_in[1];
    const float* self_table   = (const float*)d_in[2];
    const float* neigh_table  = (const float*)d_in[3];
    const float* center       = (const float*)d_in[4];
    const float* cluster_mask = (const float*)d_in[5];
    const float* weight       = (const float*)d_in[6];
    const float* alpha        = (const float*)d_in[7];
    float* out = (float*)d_out;

    int B = in_sizes[0];
    int S = in_sizes[1] / B;
    int E = in_sizes[6] / (2 * FDIM);

    int Np = ((E + 15) / 16) * 16;
    ushort_t* Wb = (ushort_t*)d_ws;   // Np x 256 bf16

    long totalW = (long)Np * 256;
    long validW = (long)E * 256;
    int blksW = (int)((totalW + 1023) / 1024);
    pack_weight<<<blksW, 256, 0, stream>>>(weight, Wb, totalW, validW);

    int nblk = (B + 7) / 8;
    fused_agg<<<nblk, 512, 0, stream>>>(
        nodes, neigh_idx, self_table, neigh_table, center, cluster_mask, alpha,
        Wb, out, B, S, E);
}

// Round 4
// 363.347 us; speedup vs baseline: 2.1442x; 2.1442x over previous
//
#include <hip/hip_runtime.h>
#include <hip/hip_bf16.h>

typedef unsigned short ushort_t;
typedef __attribute__((ext_vector_type(4))) float v4f;
typedef __attribute__((ext_vector_type(8))) short v8s;

#define FDIM 128
#define KCLUST 16
#define CSTRIDE 264   // combined-row stride in bf16 elems

__device__ __forceinline__ ushort_t f2bf(float x) {
    unsigned int u = __float_as_uint(x);
    unsigned int r = (u + 0x7fffu + ((u >> 16) & 1u)) >> 16;
    return (ushort_t)r;
}

__device__ __forceinline__ float wave_reduce_sum(float v) {
    #pragma unroll
    for (int off = 32; off > 0; off >>= 1) v += __shfl_xor(v, off, 64);
    return v;
}

// ---------------------------------------------------------------------------
// Kernel 1: cast weight (E x 256 f32) -> bf16, padded to Np rows (zeros).
// ---------------------------------------------------------------------------
__global__ void pack_weight(const float* __restrict__ W, ushort_t* __restrict__ Wb,
                            long total, long valid) {
    long i = ((long)blockIdx.x * blockDim.x + threadIdx.x) * 4;
    if (i >= total) return;
    float4 v;
    if (i < valid) v = *(const float4*)(W + i);
    else           v = make_float4(0.f, 0.f, 0.f, 0.f);
    ushort_t* dst = Wb + i;
    dst[0] = f2bf(v.x); dst[1] = f2bf(v.y); dst[2] = f2bf(v.z); dst[3] = f2bf(v.w);
}

// ---------------------------------------------------------------------------
// Kernel 2 (fused): 512 threads = 8 waves, one row b per wave.
// __launch_bounds__(512,4): VGPR cap 128 — per-lane constant arrays
// (cc[32]+anc[32]+mk[32]) demand ~120 regs; the (512,6) cap of 85 in the
// previous round spilled them to scratch (1.5 GB FETCH). DO NOT lower.
// ---------------------------------------------------------------------------
__global__ __launch_bounds__(512, 4) void fused_agg(
    const int* __restrict__ nodes, const int* __restrict__ neigh_idx,
    const float* __restrict__ self_table, const float* __restrict__ neigh_table,
    const float* __restrict__ center, const float* __restrict__ cluster_mask,
    const float* __restrict__ alpha, const ushort_t* __restrict__ Wb,
    float* __restrict__ out, int B, int S, int E) {

    __shared__ __align__(16) ushort_t comb[16 * CSTRIDE];
    __shared__ __align__(16) float nbuf[8 * 144];   // per-wave swizzled neigh vec
    __shared__ __align__(16) float qbuf[8 * 16];    // per-wave att*q[16]

    int t = threadIdx.x;
    int lane = t & 63, wave = t >> 6;
    int l16 = lane & 15, quad = lane >> 4;   // cluster k = l16, feat-block = quad

    // zero comb rows 8..15 (they feed the m=16 MFMA tile as padding)
    for (int i = t; i < (8 * CSTRIDE) / 2; i += 512)
        ((unsigned*)(comb + 8 * CSTRIDE))[i] = 0u;

    // per-lane constants
    float as0 = alpha[lane], as1 = alpha[lane + 64];

    // center in cluster layout: cc[j] = center[l16][quad*32 + j]
    float cc[32];
    {
        const float* cb = center + l16 * FDIM + quad * 32;
        #pragma unroll
        for (int j = 0; j < 32; j += 4) {
            float4 v = *(const float4*)(cb + j);
            cc[j] = v.x; cc[j+1] = v.y; cc[j+2] = v.z; cc[j+3] = v.w;
        }
    }
    // a_neigh in cluster layout: anc[j] = alpha[128 + quad*32 + j]
    float anc[32];
    {
        const float* ab = alpha + 128 + quad * 32;
        #pragma unroll
        for (int j = 0; j < 32; j += 4) {
            float4 v = *(const float4*)(ab + j);
            anc[j] = v.x; anc[j+1] = v.y; anc[j+2] = v.z; anc[j+3] = v.w;
        }
    }
    // mask in feature layout
    float mk0[KCLUST], mk1[KCLUST];
    #pragma unroll
    for (int kk = 0; kk < KCLUST; kk++) {
        mk0[kk] = cluster_mask[kk * FDIM + lane];
        mk1[kk] = cluster_mask[kk * FDIM + 64 + lane];
    }

    int b0 = blockIdx.x * 8;
    int b = b0 + wave;
    float* nb = nbuf + wave * 144;
    float* qb = qbuf + wave * 16;
    ushort_t* crow = comb + wave * CSTRIDE;

    if (b < B) {
        size_t node = (size_t)nodes[b];
        float s0 = self_table[node * FDIM + lane];
        float s1 = self_table[node * FDIM + 64 + lane];
        float ls = wave_reduce_sum(s0 * as0 + s1 * as1);

        float acc0 = 0.f, acc1 = 0.f, attsum = 0.f;
        const int* nidx = neigh_idx + (size_t)b * S;
        size_t g = (size_t)nidx[0];
        float n0 = neigh_table[g * FDIM + lane];
        float n1 = neigh_table[g * FDIM + 64 + lane];
        for (int s = 0; s < S; s++) {
            float cn0 = n0, cn1 = n1;
            if (s + 1 < S) {
                g = (size_t)nidx[s + 1];
                n0 = neigh_table[g * FDIM + lane];
                n1 = neigh_table[g * FDIM + 64 + lane];
            }
            // stage neigh vec (swizzled: float f at idx f + (f>>5)*4)
            nb[lane + (lane >> 5) * 4] = cn0;
            int f2 = lane + 64;
            nb[f2 + (f2 >> 5) * 4] = cn1;
            // cluster layout: d_k over 32 feats + logit partial, same pass
            float d = 0.f, lnp = 0.f;
            const float* nbb = nb + quad * 36;
            #pragma unroll
            for (int i = 0; i < 8; i++) {
                float4 f4 = *(const float4*)(nbb + i * 4);
                float t0 = f4.x - cc[i*4+0]; d = fmaf(t0, t0, d); lnp = fmaf(f4.x, anc[i*4+0], lnp);
                float t1 = f4.y - cc[i*4+1]; d = fmaf(t1, t1, d); lnp = fmaf(f4.y, anc[i*4+1], lnp);
                float t2 = f4.z - cc[i*4+2]; d = fmaf(t2, t2, d); lnp = fmaf(f4.z, anc[i*4+2], lnp);
                float t3 = f4.w - cc[i*4+3]; d = fmaf(t3, t3, d); lnp = fmaf(f4.w, anc[i*4+3], lnp);
            }
            d   += __shfl_xor(d, 16, 64);   d   += __shfl_xor(d, 32, 64);
            lnp += __shfl_xor(lnp, 16, 64); lnp += __shfl_xor(lnp, 32, 64);
            float att = __expf(fmaxf(ls + lnp, 0.f));
            float q = __fdividef(att, d + 1.0f);   // att*q folded
            if (lane < 16) qb[lane] = q;
            float4 q0 = *(const float4*)(qb + 0);
            float4 q1 = *(const float4*)(qb + 4);
            float4 q2 = *(const float4*)(qb + 8);
            float4 q3 = *(const float4*)(qb + 12);
            float m0, m1;
            m0  = q0.x*mk0[0]  + q0.y*mk0[1]  + q0.z*mk0[2]  + q0.w*mk0[3];
            m0 += q1.x*mk0[4]  + q1.y*mk0[5]  + q1.z*mk0[6]  + q1.w*mk0[7];
            m0 += q2.x*mk0[8]  + q2.y*mk0[9]  + q2.z*mk0[10] + q2.w*mk0[11];
            m0 += q3.x*mk0[12] + q3.y*mk0[13] + q3.z*mk0[14] + q3.w*mk0[15];
            m1  = q0.x*mk1[0]  + q0.y*mk1[1]  + q0.z*mk1[2]  + q0.w*mk1[3];
            m1 += q1.x*mk1[4]  + q1.y*mk1[5]  + q1.z*mk1[6]  + q1.w*mk1[7];
            m1 += q2.x*mk1[8]  + q2.y*mk1[9]  + q2.z*mk1[10] + q2.w*mk1[11];
            m1 += q3.x*mk1[12] + q3.y*mk1[13] + q3.z*mk1[14] + q3.w*mk1[15];
            acc0 += cn0 * m0;
            acc1 += cn1 * m1;
            attsum += att;
        }
        float inv = __fdividef(1.0f, attsum);
        crow[lane]       = f2bf(s0);
        crow[lane + 64]  = f2bf(s1);
        crow[lane + 128] = f2bf(acc0 * inv);
        crow[lane + 192] = f2bf(acc1 * inv);
    } else {
        crow[lane] = 0; crow[lane + 64] = 0;
        crow[lane + 128] = 0; crow[lane + 192] = 0;
    }
    __syncthreads();

    // ---------------- phase B ----------------
    v8s afr[8];
    #pragma unroll
    for (int kk = 0; kk < 8; kk++)
        afr[kk] = *(const v8s*)(comb + l16 * CSTRIDE + kk * 32 + quad * 8);

    int Ntiles = (E + 15) >> 4;
    for (int nt = wave; nt < Ntiles; nt += 8) {
        const ushort_t* wrow = Wb + ((size_t)(nt * 16 + l16)) * 256 + quad * 8;
        v4f acc = {0.f, 0.f, 0.f, 0.f};
        #pragma unroll
        for (int kk = 0; kk < 8; kk++) {
            v8s bfr = *(const v8s*)(wrow + kk * 32);
            acc = __builtin_amdgcn_mfma_f32_16x16x32_bf16(afr[kk], bfr, acc, 0, 0, 0);
        }
        int gcol = nt * 16 + l16;
        if (gcol < E) {
            #pragma unroll
            for (int rr = 0; rr < 4; rr++) {
                int r16 = quad * 4 + rr;
                if (r16 < 8) {
                    int grow = b0 + r16;
                    if (grow < B)
                        out[(size_t)grow * E + gcol] = fmaxf(acc[rr], 0.f);
                }
            }
        }
    }
}

extern "C" void kernel_launch(void* const* d_in, const int* in_sizes, int n_in,
                              void* d_out, int out_size, void* d_ws, size_t ws_size,
                              hipStream_t stream) {
    const int*   nodes        = (const int*)d_in[0];
    const int*   neigh_idx    = (const int*)d_in[1];
    const float* self_table   = (const float*)d_in[2];
    const float* neigh_table  = (const float*)d_in[3];
    const float* center       = (const float*)d_in[4];
    const float* cluster_mask = (const float*)d_in[5];
    const float* weight       = (const float*)d_in[6];
    const float* alpha        = (const float*)d_in[7];
    float* out = (float*)d_out;

    int B = in_sizes[0];
    int S = in_sizes[1] / B;
    int E = in_sizes[6] / (2 * FDIM);

    int Np = ((E + 15) / 16) * 16;
    ushort_t* Wb = (ushort_t*)d_ws;   // Np x 256 bf16

    long totalW = (long)Np * 256;
    long validW = (long)E * 256;
    int blksW = (int)((totalW + 1023) / 1024);
    pack_weight<<<blksW, 256, 0, stream>>>(weight, Wb, totalW, validW);

    int nblk = (B + 7) / 8;
    fused_agg<<<nblk, 512, 0, stream>>>(
        nodes, neigh_idx, self_table, neigh_table, center, cluster_mask, alpha,
        Wb, out, B, S, E);
}

// Round 5
// 285.163 us; speedup vs baseline: 2.7320x; 1.2742x over previous
//
#include <hip/hip_runtime.h>
#include <hip/hip_bf16.h>

typedef unsigned short ushort_t;
typedef __attribute__((ext_vector_type(4))) float v4f;
typedef __attribute__((ext_vector_type(8))) short v8s;

#define FDIM 128
#define KCLUST 16
#define CSTRIDE 264   // combined-row stride in bf16 elems

__device__ __forceinline__ ushort_t f2bf(float x) {
    unsigned int u = __float_as_uint(x);
    unsigned int r = (u + 0x7fffu + ((u >> 16) & 1u)) >> 16;
    return (ushort_t)r;
}

__device__ __forceinline__ float wave_reduce_sum(float v) {
    #pragma unroll
    for (int off = 32; off > 0; off >>= 1) v += __shfl_xor(v, off, 64);
    return v;
}

// ---------------------------------------------------------------------------
// Kernel 1: cast weight (E x 256 f32) -> bf16, padded to Np rows (zeros).
// ---------------------------------------------------------------------------
__global__ void pack_weight(const float* __restrict__ W, ushort_t* __restrict__ Wb,
                            long total, long valid) {
    long i = ((long)blockIdx.x * blockDim.x + threadIdx.x) * 4;
    if (i >= total) return;
    float4 v;
    if (i < valid) v = *(const float4*)(W + i);
    else           v = make_float4(0.f, 0.f, 0.f, 0.f);
    ushort_t* dst = Wb + i;
    dst[0] = f2bf(v.x); dst[1] = f2bf(v.y); dst[2] = f2bf(v.z); dst[3] = f2bf(v.w);
}

// ---------------------------------------------------------------------------
// Kernel 2 (fused): 256 threads = 4 waves, ONE row b per wave, 5000 blocks.
// Register budget note (R3/R4 post-mortem): per-lane constant arrays must
// stay at cc[32]+mk0[16]+mk1[16] (VGPR=72, no spill at 256-thread blocks).
// Adding anc[32] or using 512-thread blocks made the allocator spill to
// scratch (WRITE_SIZE 10 MB -> 80-534 MB). Attention logit uses the 6-shfl
// butterfly: it is independent of the distance chain, so it hides.
// ---------------------------------------------------------------------------
__global__ __launch_bounds__(256) void fused_agg(
    const int* __restrict__ nodes, const int* __restrict__ neigh_idx,
    const float* __restrict__ self_table, const float* __restrict__ neigh_table,
    const float* __restrict__ center, const float* __restrict__ cluster_mask,
    const float* __restrict__ alpha, const ushort_t* __restrict__ Wb,
    float* __restrict__ out, int B, int S, int E) {

    __shared__ __align__(16) ushort_t comb[16 * CSTRIDE];
    __shared__ __align__(16) float nbuf[4 * 144];   // per-wave swizzled neigh vec
    __shared__ __align__(16) float qbuf[4 * 16];    // per-wave att*q[16]

    int t = threadIdx.x;
    int lane = t & 63, wave = t >> 6;
    int l16 = lane & 15, quad = lane >> 4;   // cluster k = l16, feat-block = quad

    // zero comb rows 4..15 (padding rows of the m=16 MFMA tile)
    for (int i = t; i < (12 * CSTRIDE) / 2; i += 256)
        ((unsigned*)(comb + 4 * CSTRIDE))[i] = 0u;

    // per-lane constants (feature layout)
    float as0 = alpha[lane],       as1 = alpha[lane + 64];
    float an0 = alpha[128 + lane], an1 = alpha[192 + lane];

    // center in cluster layout: cc[j] = center[l16][quad*32 + j]
    float cc[32];
    {
        const float* cb = center + l16 * FDIM + quad * 32;
        #pragma unroll
        for (int j = 0; j < 32; j += 4) {
            float4 v = *(const float4*)(cb + j);
            cc[j] = v.x; cc[j+1] = v.y; cc[j+2] = v.z; cc[j+3] = v.w;
        }
    }
    // mask in feature layout
    float mk0[KCLUST], mk1[KCLUST];
    #pragma unroll
    for (int kk = 0; kk < KCLUST; kk++) {
        mk0[kk] = cluster_mask[kk * FDIM + lane];
        mk1[kk] = cluster_mask[kk * FDIM + 64 + lane];
    }

    int b0 = blockIdx.x * 4;
    int b = b0 + wave;
    float* nb = nbuf + wave * 144;
    float* qb = qbuf + wave * 16;
    ushort_t* crow = comb + wave * CSTRIDE;

    if (b < B) {
        size_t node = (size_t)nodes[b];
        float s0 = self_table[node * FDIM + lane];
        float s1 = self_table[node * FDIM + 64 + lane];
        float ls = wave_reduce_sum(s0 * as0 + s1 * as1);

        float acc0 = 0.f, acc1 = 0.f, attsum = 0.f;
        const int* nidx = neigh_idx + (size_t)b * S;
        size_t g = (size_t)nidx[0];
        float n0 = neigh_table[g * FDIM + lane];
        float n1 = neigh_table[g * FDIM + 64 + lane];
        for (int s = 0; s < S; s++) {
            float cn0 = n0, cn1 = n1;
            if (s + 1 < S) {
                g = (size_t)nidx[s + 1];
                n0 = neigh_table[g * FDIM + lane];
                n1 = neigh_table[g * FDIM + 64 + lane];
            }
            // attention logit (butterfly — independent of distance chain)
            float ln = wave_reduce_sum(cn0 * an0 + cn1 * an1);
            float att = __expf(fmaxf(ls + ln, 0.f));
            // stage neigh vec (swizzled: float f at idx f + (f>>5)*4)
            nb[lane + (lane >> 5) * 4] = cn0;
            int f2 = lane + 64;
            nb[f2 + (f2 >> 5) * 4] = cn1;
            // cluster layout: d_k = sum (n-c_k)^2 over this quad's 32 feats
            float d = 0.f;
            const float* nbb = nb + quad * 36;
            #pragma unroll
            for (int i = 0; i < 8; i++) {
                float4 f4 = *(const float4*)(nbb + i * 4);
                float t0 = f4.x - cc[i*4+0]; d = fmaf(t0, t0, d);
                float t1 = f4.y - cc[i*4+1]; d = fmaf(t1, t1, d);
                float t2 = f4.z - cc[i*4+2]; d = fmaf(t2, t2, d);
                float t3 = f4.w - cc[i*4+3]; d = fmaf(t3, t3, d);
            }
            d += __shfl_xor(d, 16, 64);
            d += __shfl_xor(d, 32, 64);
            float q = __fdividef(att, d + 1.0f);   // att*q folded
            if (lane < 16) qb[lane] = q;
            float4 q0 = *(const float4*)(qb + 0);
            float4 q1 = *(const float4*)(qb + 4);
            float4 q2 = *(const float4*)(qb + 8);
            float4 q3 = *(const float4*)(qb + 12);
            float m0, m1;
            m0  = q0.x*mk0[0]  + q0.y*mk0[1]  + q0.z*mk0[2]  + q0.w*mk0[3];
            m0 += q1.x*mk0[4]  + q1.y*mk0[5]  + q1.z*mk0[6]  + q1.w*mk0[7];
            m0 += q2.x*mk0[8]  + q2.y*mk0[9]  + q2.z*mk0[10] + q2.w*mk0[11];
            m0 += q3.x*mk0[12] + q3.y*mk0[13] + q3.z*mk0[14] + q3.w*mk0[15];
            m1  = q0.x*mk1[0]  + q0.y*mk1[1]  + q0.z*mk1[2]  + q0.w*mk1[3];
            m1 += q1.x*mk1[4]  + q1.y*mk1[5]  + q1.z*mk1[6]  + q1.w*mk1[7];
            m1 += q2.x*mk1[8]  + q2.y*mk1[9]  + q2.z*mk1[10] + q2.w*mk1[11];
            m1 += q3.x*mk1[12] + q3.y*mk1[13] + q3.z*mk1[14] + q3.w*mk1[15];
            acc0 += cn0 * m0;
            acc1 += cn1 * m1;
            attsum += att;
        }
        float inv = __fdividef(1.0f, attsum);
        crow[lane]       = f2bf(s0);
        crow[lane + 64]  = f2bf(s1);
        crow[lane + 128] = f2bf(acc0 * inv);
        crow[lane + 192] = f2bf(acc1 * inv);
    } else {
        crow[lane] = 0; crow[lane + 64] = 0;
        crow[lane + 128] = 0; crow[lane + 192] = 0;
    }
    __syncthreads();

    // ---------------- phase B ----------------
    v8s afr[8];
    #pragma unroll
    for (int kk = 0; kk < 8; kk++)
        afr[kk] = *(const v8s*)(comb + l16 * CSTRIDE + kk * 32 + quad * 8);

    int Ntiles = (E + 15) >> 4;
    for (int nt = wave; nt < Ntiles; nt += 4) {
        const ushort_t* wrow = Wb + ((size_t)(nt * 16 + l16)) * 256 + quad * 8;
        v4f acc = {0.f, 0.f, 0.f, 0.f};
        #pragma unroll
        for (int kk = 0; kk < 8; kk++) {
            v8s bfr = *(const v8s*)(wrow + kk * 32);
            acc = __builtin_amdgcn_mfma_f32_16x16x32_bf16(afr[kk], bfr, acc, 0, 0, 0);
        }
        int gcol = nt * 16 + l16;
        if (gcol < E) {
            #pragma unroll
            for (int rr = 0; rr < 4; rr++) {
                int r16 = quad * 4 + rr;
                if (r16 < 4) {
                    int grow = b0 + r16;
                    if (grow < B)
                        out[(size_t)grow * E + gcol] = fmaxf(acc[rr], 0.f);
                }
            }
        }
    }
}

extern "C" void kernel_launch(void* const* d_in, const int* in_sizes, int n_in,
                              void* d_out, int out_size, void* d_ws, size_t ws_size,
                              hipStream_t stream) {
    const int*   nodes        = (const int*)d_in[0];
    const int*   neigh_idx    = (const int*)d_in[1];
    const float* self_table   = (const float*)d_in[2];
    const float* neigh_table  = (const float*)d_in[3];
    const float* center       = (const float*)d_in[4];
    const float* cluster_mask = (const float*)d_in[5];
    const float* weight       = (const float*)d_in[6];
    const float* alpha        = (const float*)d_in[7];
    float* out = (float*)d_out;

    int B = in_sizes[0];
    int S = in_sizes[1] / B;
    int E = in_sizes[6] / (2 * FDIM);

    int Np = ((E + 15) / 16) * 16;
    ushort_t* Wb = (ushort_t*)d_ws;   // Np x 256 bf16

    long totalW = (long)Np * 256;
    long validW = (long)E * 256;
    int blksW = (int)((totalW + 1023) / 1024);
    pack_weight<<<blksW, 256, 0, stream>>>(weight, Wb, totalW, validW);

    int nblk = (B + 3) / 4;
    fused_agg<<<nblk, 256, 0, stream>>>(
        nodes, neigh_idx, self_table, neigh_table, center, cluster_mask, alpha,
        Wb, out, B, S, E);
}